// Round 8
// baseline (167.045 us; speedup 1.0000x reference)
//
#include <hip/hip_runtime.h>
#include <hip/hip_bf16.h>

typedef unsigned long long u64;
typedef unsigned int u32;
typedef unsigned short u16;

#define MAXD 5
#define BSH  6
#define BN   64        // nodes per bucket
#define NW   512       // edge chunks (= chunk_sort blocks)
#define NTH  256
#define NBMAX 1024     // scan padding (NB = 782)
#define HEMPTY 0xFFFFFFFFu

// ---------------------------------------------------------------------------
// R7 lesson: scatter_setup was 56us -- latency-bound on the global
// reservation-atomic -> LDS-cursor -> random-4B-store chain (occupancy 9%,
// WRITE 27MB from write-through + sector amplification).
// R8: deterministic chunk-local counting sort. Block c owns edges
// [c*CE,(c+1)*CE) and output recs[c*CAPC ...] (every edge = exactly 2
// records -> static offsets, ZERO global atomics). Sort happens in LDS
// (hist -> scan -> place), written out coalesced, plus a u16 segment table
// segtab[c][bucket]. Level kernels walk the NW segments per bucket.
// Depth-1 frontier (NFg) is pushed during pass B via a 64-source LDS hash
// (~2K global atomics total). Levels/epilogues unchanged from R7.
//
// ws: NFg[N] V[N] CNT[N] F2[N] F3[N] (u64) | srcPack[64] nvalid (u32)
//     recs[NW*CAPC] (u32) | segtab[NW*(NB+1)] (u16)
// ---------------------------------------------------------------------------

__global__ __launch_bounds__(NTH) void chunk_sort(
    const int* __restrict__ h, const int* __restrict__ t, int E, int CE, int CAPC,
    int NB, u32* __restrict__ recs, u16* __restrict__ segtab,
    const int* __restrict__ anchor, int A,
    u64* __restrict__ NFg, u32* __restrict__ srcPack, int* __restrict__ nvalid) {
    extern __shared__ u32 sh[];
    u32* s     = sh;                 // [NBMAX] counts -> exclusive offsets
    u32* cur   = sh + NBMAX;         // [NB] counts (pass A) -> cursors (pass B)
    u32* hsKey = cur + NB;           // [128]
    u32* hsBit = hsKey + 128;        // [128]
    u32* buf   = hsBit + 128;        // [CAPC] sorted records
    int tid = threadIdx.x, c = blockIdx.x;
    int lo = c * CE, hi = min(E, lo + CE);
    int nrec = 2 * (hi - lo);

    for (int i = tid; i < NB; i += NTH) cur[i] = 0u;
    if (tid < 128) hsKey[tid] = HEMPTY;
    __syncthreads();

    if (tid < 64) {  // every block: anchor gather + shfl dedup + hash insert
        int K = 2 * A;  // 64
        int a_ = (tid < K) ? anchor[(tid < A) ? tid : (tid - A)] : 0;
        int my = (tid < K) ? ((tid < A) ? h[a_] : t[a_]) : -1;
        bool uniq = (tid < K);
        for (int j = 0; j < 64; ++j) {
            int o = __shfl(my, j, 64);
            if (j < tid && o == my) uniq = false;
        }
        u64 mask = __ballot(uniq);
        if (c == 0 && tid == 0) *nvalid = (int)__popcll(mask);
        if (uniq) {
            u32 slot = ((u32)my * 2654435761u) >> 25;
            while (atomicCAS(&hsKey[slot], HEMPTY, (u32)my) != HEMPTY)
                slot = (slot + 1) & 127u;
            hsBit[slot] = (u32)tid;
        }
        if (c == 0)
            srcPack[tid] = uniq ? (((u32)my << BSH) | (u32)tid) : HEMPTY;
    }
    __syncthreads();

    // pass A: count records per bucket
    for (int e = lo + tid; e < hi; e += NTH) {
        u32 uu = (u32)h[e], vv = (u32)t[e];
        atomicAdd(&cur[vv >> BSH], 1u);
        atomicAdd(&cur[uu >> BSH], 1u);
    }
    __syncthreads();

    // in-LDS Hillis-Steele scan (NBMAX entries, 4 per thread)
    for (int k = 0; k < NBMAX / NTH; ++k) {
        int i = tid + NTH * k;
        s[i] = (i < NB) ? cur[i] : 0u;
    }
    __syncthreads();
    for (int d = 1; d < NBMAX; d <<= 1) {
        u32 v0[NBMAX / NTH];
#pragma unroll
        for (int k = 0; k < NBMAX / NTH; ++k) {
            int i = tid + NTH * k;
            v0[k] = (i >= d) ? s[i - d] : 0u;
        }
        __syncthreads();
#pragma unroll
        for (int k = 0; k < NBMAX / NTH; ++k) s[tid + NTH * k] += v0[k];
        __syncthreads();
    }
    // inclusive -> exclusive; reset cursors; publish segment table
    for (int i = tid; i < NB; i += NTH) {
        u32 excl = s[i] - cur[i];
        s[i] = excl;
        cur[i] = 0u;
        segtab[c * (NB + 1) + i] = (u16)excl;
    }
    if (tid == 0) segtab[c * (NB + 1) + NB] = (u16)nrec;
    __syncthreads();

    auto srcMask = [&](u32 src) -> u64 {
        u32 slot = (src * 2654435761u) >> 25;
        while (true) {
            u32 k = hsKey[slot];
            if (k == src) return 1ull << hsBit[slot];
            if (k == HEMPTY) return 0ull;
            slot = (slot + 1) & 127u;
        }
    };

    // pass B: place records into LDS + depth-1 NFg push
    for (int e = lo + tid; e < hi; e += NTH) {
        u32 uu = (u32)h[e], vv = (u32)t[e];
        u32 b1 = vv >> BSH;
        buf[s[b1] + atomicAdd(&cur[b1], 1u)] = (uu << BSH) | (vv & (BN - 1));
        u32 b2 = uu >> BSH;
        buf[s[b2] + atomicAdd(&cur[b2], 1u)] = (vv << BSH) | (uu & (BN - 1));
        if (uu != vv) {   // self-loop guard keeps NFg == depth-1 newly exactly
            u64 m1 = srcMask(uu);
            if (m1) atomicOr(&NFg[vv], m1);
            u64 m2 = srcMask(vv);
            if (m2) atomicOr(&NFg[uu], m2);
        }
    }
    __syncthreads();

    // coalesced write-out of the sorted chunk
    for (int i = tid; i < nrec; i += NTH) recs[c * CAPC + i] = buf[i];
}

// Gather helper pattern (macro-free, repeated in each level): thread tid
// walks chunk-segments tid, tid+NTH, ... for this bucket.

// Depth 1+2 fused: NFg IS the depth-1 frontier; LDS tile collects depth-2.
__global__ __launch_bounds__(NTH) void level12(
    const u32* __restrict__ recs, const u16* __restrict__ segtab, int CAPC, int NB,
    const u32* __restrict__ srcPack, const u64* __restrict__ NFg,
    u64* __restrict__ F2, u64* __restrict__ V, u64* __restrict__ CNT, int N) {
    __shared__ u64 NF[BN];
    __shared__ u32 srcL[64];
    int b = blockIdx.x, tid = threadIdx.x;
    if (tid < BN) NF[tid] = 0ull;
    if (tid < 64) srcL[tid] = srcPack[tid];
    __syncthreads();
    for (int c = tid; c < NW; c += NTH) {
        const u16* st = segtab + c * (NB + 1);
        u32 base = (u32)c * CAPC;
        u32 k = st[b], k1 = st[b + 1];
        for (; k < k1; ++k) {
            u32 rec = recs[base + k];
            u64 f = NFg[rec >> BSH];
            if (f) atomicOr(&NF[rec & (BN - 1)], f);
        }
    }
    __syncthreads();
    if (tid < BN) {
        int n = b * BN + tid;
        if (n < N) {
            u64 srcbit = 0ull;
            for (int k = 0; k < 64; ++k) {
                u32 p = srcL[k];
                if (p != HEMPTY && (int)(p >> BSH) == n)
                    srcbit |= 1ull << (p & (BN - 1));
            }
            u64 nf1 = NFg[n];
            u64 v1 = srcbit | nf1;
            u64 newly2 = NF[tid] & ~v1;
            V[n] = v1 | newly2;
            F2[n] = newly2;
            CNT[n] = (srcbit ? 1ull : 0ull)
                   | ((u64)__popcll(nf1) << 8)
                   | ((u64)__popcll(newly2) << 16);
        }
    }
}

// Depth 3.
__global__ __launch_bounds__(NTH) void level3(
    const u32* __restrict__ recs, const u16* __restrict__ segtab, int CAPC, int NB,
    const u64* __restrict__ Fin, u64* __restrict__ Fout,
    u64* __restrict__ V, u64* __restrict__ CNT, int N) {
    __shared__ u64 NF[BN];
    int b = blockIdx.x, tid = threadIdx.x;
    if (tid < BN) NF[tid] = 0ull;
    __syncthreads();
    for (int c = tid; c < NW; c += NTH) {
        const u16* st = segtab + c * (NB + 1);
        u32 base = (u32)c * CAPC;
        u32 k = st[b], k1 = st[b + 1];
        for (; k < k1; ++k) {
            u32 rec = recs[base + k];
            u64 f = Fin[rec >> BSH];
            if (f) atomicOr(&NF[rec & (BN - 1)], f);
        }
    }
    __syncthreads();
    if (tid < BN) {
        int n = b * BN + tid;
        if (n < N) {
            u64 vis = V[n];
            u64 newly = NF[tid] & ~vis;
            Fout[n] = newly;
            if (newly) {
                V[n] = vis | newly;
                CNT[n] += (u64)__popcll(newly) << 24;
            }
        }
    }
}

// Depth 4 fused with the output matmul (quad lane q writes float4 q, D=16).
__global__ __launch_bounds__(NTH) void level4_fin(
    const u32* __restrict__ recs, const u16* __restrict__ segtab, int CAPC, int NB,
    const u64* __restrict__ Fin, const u64* __restrict__ V,
    const u64* __restrict__ CNT, const int* __restrict__ nvalid,
    const float* __restrict__ embed, float* __restrict__ out, int N) {
    __shared__ u64 NF[BN];
    int b = blockIdx.x, tid = threadIdx.x;
    if (tid < BN) NF[tid] = 0ull;
    __syncthreads();
    for (int c = tid; c < NW; c += NTH) {
        const u16* st = segtab + c * (NB + 1);
        u32 base = (u32)c * CAPC;
        u32 k = st[b], k1 = st[b + 1];
        for (; k < k1; ++k) {
            u32 rec = recs[base + k];
            u64 f = Fin[rec >> BSH];
            if (f) atomicOr(&NF[rec & (BN - 1)], f);
        }
    }
    __syncthreads();
    int nl = tid >> 2, q = tid & 3;   // 64 nodes x 4 float4 quads
    int n = b * BN + nl;
    if (n >= N) return;
    u64 vis = V[n];
    int c4 = __popcll(NF[nl] & ~vis);
    u64 c = CNT[n];
    int nv = *nvalid;
    float inv = 1.0f / (float)(nv > 0 ? nv : 1);
    float cd[MAXD + 1];
    int total = c4;
#pragma unroll
    for (int d = 0; d < 4; ++d) {
        int x = (int)((c >> (8 * d)) & 0xffull);
        total += x;
        cd[d] = (float)x;
    }
    cd[4] = (float)c4;
    cd[5] = (float)(nv - total);  // depth-5 + unreached

    const float4* e4 = (const float4*)embed;  // [6][4] float4 rows
    float4 acc = {0.f, 0.f, 0.f, 0.f};
#pragma unroll
    for (int d = 0; d <= MAXD; ++d) {
        float4 e = e4[d * 4 + q];
        acc.x += cd[d] * e.x; acc.y += cd[d] * e.y;
        acc.z += cd[d] * e.z; acc.w += cd[d] * e.w;
    }
    acc.x *= inv; acc.y *= inv; acc.z *= inv; acc.w *= inv;
    ((float4*)(out + (size_t)n * 16))[q] = acc;
}

extern "C" void kernel_launch(void* const* d_in, const int* in_sizes, int n_in,
                              void* d_out, int out_size, void* d_ws, size_t ws_size,
                              hipStream_t stream) {
    const int*   h      = (const int*)d_in[0];
    const int*   t      = (const int*)d_in[1];
    const int*   anchor = (const int*)d_in[2];
    const float* embed  = (const float*)d_in[4];
    float*       out    = (float*)d_out;

    int E = in_sizes[0];
    int A = in_sizes[2];               // 32 anchor triples -> 64 sources
    int D = in_sizes[4] / (MAXD + 1);  // 16
    int N = out_size / D;              // 50000
    int NB = (N + BN - 1) >> BSH;      // 782 buckets
    int CE = (E + NW - 1) / NW;        // 1563 edges per chunk
    int CAPC = 2 * CE;                 // 3126 records per chunk (exact)
    (void)D;

    u64* NFg = (u64*)d_ws;
    u64* V   = NFg + N;
    u64* CNT = V + N;
    u64* F2  = CNT + N;
    u64* F3  = F2 + N;
    u32* srcPack = (u32*)(F3 + N);
    int* nvalid  = (int*)(srcPack + 64);
    u32* recs    = (u32*)(nvalid + 1);
    u16* segtab  = (u16*)(recs + (size_t)NW * CAPC);

    // Only NFg needs zeroing (V/CNT/F2/F3 fully written; recs/segtab fully
    // written by chunk_sort).
    hipMemsetAsync(NFg, 0, (size_t)N * 8, stream);

    size_t shmem = (NBMAX + NB + 256) * sizeof(u32) + (size_t)CAPC * sizeof(u32);
    chunk_sort<<<NW, NTH, shmem, stream>>>(h, t, E, CE, CAPC, NB, recs, segtab,
                                           anchor, A, NFg, srcPack, nvalid);

    level12<<<NB, NTH, 0, stream>>>(recs, segtab, CAPC, NB, srcPack, NFg,
                                    F2, V, CNT, N);
    level3<<<NB, NTH, 0, stream>>>(recs, segtab, CAPC, NB, F2, F3, V, CNT, N);
    level4_fin<<<NB, NTH, 0, stream>>>(recs, segtab, CAPC, NB, F3, V, CNT,
                                       nvalid, embed, out, N);
}

// Round 9
// 138.829 us; speedup vs baseline: 1.2032x; 1.2032x over previous
//
#include <hip/hip_runtime.h>
#include <hip/hip_bf16.h>

typedef unsigned long long u64;
typedef unsigned int u32;
typedef unsigned short u16;

#define MAXD 5
#define BSH  6
#define BN   64        // nodes per bucket
#define NW   512       // edge chunks (= chunk_sort blocks)
#define NTH  256
#define NBMAX 1024     // scan padding in chunk_sort (NB = 782)
#define CAPG 2816      // bucket-major record capacity (mean 2046, +17 sigma)
#define HEMPTY 0xFFFFFFFFu

// ---------------------------------------------------------------------------
// R7: global-atomic scatter = 56us (latency chain).  R8: chunk-local LDS
// sort killed that, but per-chunk segment walks in ALL levels killed MLP
// (serial ~6-record segments) -> net regression.
// R9: walk the segments ONCE. level12 converts chunk-major -> bucket-major
// (coalesced recs2 write) while doing its depth-2 gather: flat record index
// j + LDS binary search over the 512-segment prefix -> 4 independent
// records in flight. Levels 3/4 use R7-proven contiguous 4-wide gathers.
//
// ws: NFg[N] V[N] CNT[N] F2[N] F3[N] (u64) | srcPack[64] nvalid bucketCnt[NB]
//     (u32) | recs[NW*CAPC] (u32) | segtab[NW*(NB+1)] (u16) | recs2[NB*CAPG]
// ---------------------------------------------------------------------------

__global__ __launch_bounds__(NTH) void chunk_sort(
    const int* __restrict__ h, const int* __restrict__ t, int E, int CE, int CAPC,
    int NB, u32* __restrict__ recs, u16* __restrict__ segtab,
    const int* __restrict__ anchor, int A,
    u64* __restrict__ NFg, u32* __restrict__ srcPack, int* __restrict__ nvalid) {
    extern __shared__ u32 sh[];
    u32* s     = sh;                 // [NBMAX] counts -> exclusive offsets
    u32* cur   = sh + NBMAX;         // [NB]
    u32* hsKey = cur + NB;           // [128]
    u32* hsBit = hsKey + 128;        // [128]
    u32* buf   = hsBit + 128;        // [CAPC]
    int tid = threadIdx.x, c = blockIdx.x;
    int lo = c * CE, hi = min(E, lo + CE);
    int nrec = 2 * (hi - lo);

    for (int i = tid; i < NB; i += NTH) cur[i] = 0u;
    if (tid < 128) hsKey[tid] = HEMPTY;
    __syncthreads();

    if (tid < 64) {  // anchor gather + shfl dedup + hash insert (every block)
        int K = 2 * A;  // 64
        int a_ = (tid < K) ? anchor[(tid < A) ? tid : (tid - A)] : 0;
        int my = (tid < K) ? ((tid < A) ? h[a_] : t[a_]) : -1;
        bool uniq = (tid < K);
        for (int j = 0; j < 64; ++j) {
            int o = __shfl(my, j, 64);
            if (j < tid && o == my) uniq = false;
        }
        u64 mask = __ballot(uniq);
        if (c == 0 && tid == 0) *nvalid = (int)__popcll(mask);
        if (uniq) {
            u32 slot = ((u32)my * 2654435761u) >> 25;
            while (atomicCAS(&hsKey[slot], HEMPTY, (u32)my) != HEMPTY)
                slot = (slot + 1) & 127u;
            hsBit[slot] = (u32)tid;
        }
        if (c == 0)
            srcPack[tid] = uniq ? (((u32)my << BSH) | (u32)tid) : HEMPTY;
    }
    __syncthreads();

    for (int e = lo + tid; e < hi; e += NTH) {   // pass A: hist
        u32 uu = (u32)h[e], vv = (u32)t[e];
        atomicAdd(&cur[vv >> BSH], 1u);
        atomicAdd(&cur[uu >> BSH], 1u);
    }
    __syncthreads();

    for (int k = 0; k < NBMAX / NTH; ++k) {       // LDS scan (1024 entries)
        int i = tid + NTH * k;
        s[i] = (i < NB) ? cur[i] : 0u;
    }
    __syncthreads();
    for (int d = 1; d < NBMAX; d <<= 1) {
        u32 v0[NBMAX / NTH];
#pragma unroll
        for (int k = 0; k < NBMAX / NTH; ++k) {
            int i = tid + NTH * k;
            v0[k] = (i >= d) ? s[i - d] : 0u;
        }
        __syncthreads();
#pragma unroll
        for (int k = 0; k < NBMAX / NTH; ++k) s[tid + NTH * k] += v0[k];
        __syncthreads();
    }
    for (int i = tid; i < NB; i += NTH) {
        u32 excl = s[i] - cur[i];
        s[i] = excl;
        cur[i] = 0u;
        segtab[c * (NB + 1) + i] = (u16)excl;
    }
    if (tid == 0) segtab[c * (NB + 1) + NB] = (u16)nrec;
    __syncthreads();

    auto srcMask = [&](u32 src) -> u64 {
        u32 slot = (src * 2654435761u) >> 25;
        while (true) {
            u32 k = hsKey[slot];
            if (k == src) return 1ull << hsBit[slot];
            if (k == HEMPTY) return 0ull;
            slot = (slot + 1) & 127u;
        }
    };

    for (int e = lo + tid; e < hi; e += NTH) {   // pass B: place + NFg push
        u32 uu = (u32)h[e], vv = (u32)t[e];
        u32 b1 = vv >> BSH;
        buf[s[b1] + atomicAdd(&cur[b1], 1u)] = (uu << BSH) | (vv & (BN - 1));
        u32 b2 = uu >> BSH;
        buf[s[b2] + atomicAdd(&cur[b2], 1u)] = (vv << BSH) | (uu & (BN - 1));
        if (uu != vv) {   // self-loop guard keeps NFg == depth-1 newly exactly
            u64 m1 = srcMask(uu);
            if (m1) atomicOr(&NFg[vv], m1);
            u64 m2 = srcMask(vv);
            if (m2) atomicOr(&NFg[uu], m2);
        }
    }
    __syncthreads();
    for (int i = tid; i < nrec; i += NTH) recs[c * CAPC + i] = buf[i];
}

// Depth 1+2 fused + chunk-major -> bucket-major merge.
__global__ __launch_bounds__(NTH) void level12_merge(
    const u32* __restrict__ recs, const u16* __restrict__ segtab, int CAPC, int NB,
    const u32* __restrict__ srcPack, const u64* __restrict__ NFg,
    u64* __restrict__ F2, u64* __restrict__ V, u64* __restrict__ CNT,
    u32* __restrict__ recs2, u32* __restrict__ bucketCnt, int N) {
    __shared__ u32 s0[NW];        // segment start within chunk
    __shared__ u32 loff[NW + 1];  // flat exclusive offsets
    __shared__ u64 NF[BN];
    __shared__ u32 srcL[64];
    int b = blockIdx.x, tid = threadIdx.x;
    if (tid < BN) NF[tid] = 0ull;
    if (tid < 64) srcL[tid] = srcPack[tid];
    // load segment descriptors (2 chunks per thread)
    for (int c = tid; c < NW; c += NTH) {
        const u16* st = segtab + c * (NB + 1);
        u32 a = st[b], e = st[b + 1];
        s0[c] = a;
        loff[c] = e - a;   // length, scanned below
    }
    __syncthreads();
    // Hillis-Steele scan of 512 lengths (2 per thread) -> inclusive
    for (int d = 1; d < NW; d <<= 1) {
        u32 v0[NW / NTH];
#pragma unroll
        for (int k = 0; k < NW / NTH; ++k) {
            int i = tid + NTH * k;
            v0[k] = (i >= d) ? loff[i - d] : 0u;
        }
        __syncthreads();
#pragma unroll
        for (int k = 0; k < NW / NTH; ++k) loff[tid + NTH * k] += v0[k];
        __syncthreads();
    }
    // inclusive -> exclusive in place (shift): recompute as excl = incl - len
    u32 T;
    {
        if (tid == 0) T = loff[NW - 1];
        // rebuild exclusive: each entry excl[c] = incl[c] - len[c]; len = incl[c]-incl[c-1]
        // simpler: store exclusive into loff by shifting right
        u32 tmp[NW / NTH];
#pragma unroll
        for (int k = 0; k < NW / NTH; ++k) {
            int i = tid + NTH * k;
            tmp[k] = (i == 0) ? 0u : loff[i - 1];
        }
        __syncthreads();
#pragma unroll
        for (int k = 0; k < NW / NTH; ++k) {
            int i = tid + NTH * k;
            if (i == 0) { /* loff[NW] gets total below */ }
        }
        if (tid == 0) loff[NW] = loff[NW - 1];
        __syncthreads();
#pragma unroll
        for (int k = 0; k < NW / NTH; ++k) loff[tid + NTH * k] = tmp[k];
        __syncthreads();
        T = loff[NW];
    }
    u32 o0 = (u32)b * CAPG;

    auto fetch = [&](u32 j) -> u32 {
        int c = 0;
#pragma unroll
        for (int step = 256; step >= 1; step >>= 1)
            if (c + step <= NW - 1 && loff[c + step] <= j) c += step;
        u32 rec = recs[(u32)c * CAPC + s0[c] + (j - loff[c])];
        if (j < (u32)CAPG) recs2[o0 + j] = rec;   // coalesced bucket-major copy
        return rec;
    };

    u32 j = tid;
    for (; j + 3u * NTH < T; j += 4u * NTH) {
        u32 r0 = fetch(j), r1 = fetch(j + NTH);
        u32 r2 = fetch(j + 2 * NTH), r3 = fetch(j + 3 * NTH);
        u64 f0 = NFg[r0 >> BSH], f1 = NFg[r1 >> BSH];
        u64 f2 = NFg[r2 >> BSH], f3 = NFg[r3 >> BSH];
        if (f0) atomicOr(&NF[r0 & (BN - 1)], f0);
        if (f1) atomicOr(&NF[r1 & (BN - 1)], f1);
        if (f2) atomicOr(&NF[r2 & (BN - 1)], f2);
        if (f3) atomicOr(&NF[r3 & (BN - 1)], f3);
    }
    for (; j < T; j += NTH) {
        u32 r0 = fetch(j);
        u64 f0 = NFg[r0 >> BSH];
        if (f0) atomicOr(&NF[r0 & (BN - 1)], f0);
    }
    __syncthreads();
    if (tid == 0) bucketCnt[b] = min(T, (u32)CAPG);
    if (tid < BN) {
        int n = b * BN + tid;
        if (n < N) {
            u64 srcbit = 0ull;
            for (int k = 0; k < 64; ++k) {
                u32 p = srcL[k];
                if (p != HEMPTY && (int)(p >> BSH) == n)
                    srcbit |= 1ull << (p & (BN - 1));
            }
            u64 nf1 = NFg[n];
            u64 v1 = srcbit | nf1;
            u64 newly2 = NF[tid] & ~v1;
            V[n] = v1 | newly2;
            F2[n] = newly2;
            CNT[n] = (srcbit ? 1ull : 0ull)
                   | ((u64)__popcll(nf1) << 8)
                   | ((u64)__popcll(newly2) << 16);
        }
    }
}

// Depth 3: contiguous bucket-major gather, 4-wide unrolled.
__global__ __launch_bounds__(NTH) void level3(
    const u32* __restrict__ recs2, const u32* __restrict__ bucketCnt,
    const u64* __restrict__ Fin, u64* __restrict__ Fout,
    u64* __restrict__ V, u64* __restrict__ CNT, int N) {
    __shared__ u64 NF[BN];
    int b = blockIdx.x, tid = threadIdx.x;
    u32 o0 = (u32)b * CAPG;
    u32 cnt = bucketCnt[b];
    if (tid < BN) NF[tid] = 0ull;
    __syncthreads();
    u32 r = tid;
    for (; r + 3u * NTH < cnt; r += 4u * NTH) {
        u32 c0 = recs2[o0 + r],           c1 = recs2[o0 + r + NTH];
        u32 c2 = recs2[o0 + r + 2 * NTH], c3 = recs2[o0 + r + 3 * NTH];
        u64 f0 = Fin[c0 >> BSH], f1 = Fin[c1 >> BSH];
        u64 f2 = Fin[c2 >> BSH], f3 = Fin[c3 >> BSH];
        if (f0) atomicOr(&NF[c0 & (BN - 1)], f0);
        if (f1) atomicOr(&NF[c1 & (BN - 1)], f1);
        if (f2) atomicOr(&NF[c2 & (BN - 1)], f2);
        if (f3) atomicOr(&NF[c3 & (BN - 1)], f3);
    }
    for (; r < cnt; r += NTH) {
        u32 c0 = recs2[o0 + r];
        u64 f0 = Fin[c0 >> BSH];
        if (f0) atomicOr(&NF[c0 & (BN - 1)], f0);
    }
    __syncthreads();
    if (tid < BN) {
        int n = b * BN + tid;
        if (n < N) {
            u64 vis = V[n];
            u64 newly = NF[tid] & ~vis;
            Fout[n] = newly;
            if (newly) {
                V[n] = vis | newly;
                CNT[n] += (u64)__popcll(newly) << 24;
            }
        }
    }
}

// Depth 4 fused with the output matmul (quad lane q writes float4 q, D=16).
__global__ __launch_bounds__(NTH) void level4_fin(
    const u32* __restrict__ recs2, const u32* __restrict__ bucketCnt,
    const u64* __restrict__ Fin, const u64* __restrict__ V,
    const u64* __restrict__ CNT, const int* __restrict__ nvalid,
    const float* __restrict__ embed, float* __restrict__ out, int N) {
    __shared__ u64 NF[BN];
    int b = blockIdx.x, tid = threadIdx.x;
    u32 o0 = (u32)b * CAPG;
    u32 cnt = bucketCnt[b];
    if (tid < BN) NF[tid] = 0ull;
    __syncthreads();
    u32 r = tid;
    for (; r + 3u * NTH < cnt; r += 4u * NTH) {
        u32 c0 = recs2[o0 + r],           c1 = recs2[o0 + r + NTH];
        u32 c2 = recs2[o0 + r + 2 * NTH], c3 = recs2[o0 + r + 3 * NTH];
        u64 f0 = Fin[c0 >> BSH], f1 = Fin[c1 >> BSH];
        u64 f2 = Fin[c2 >> BSH], f3 = Fin[c3 >> BSH];
        if (f0) atomicOr(&NF[c0 & (BN - 1)], f0);
        if (f1) atomicOr(&NF[c1 & (BN - 1)], f1);
        if (f2) atomicOr(&NF[c2 & (BN - 1)], f2);
        if (f3) atomicOr(&NF[c3 & (BN - 1)], f3);
    }
    for (; r < cnt; r += NTH) {
        u32 c0 = recs2[o0 + r];
        u64 f0 = Fin[c0 >> BSH];
        if (f0) atomicOr(&NF[c0 & (BN - 1)], f0);
    }
    __syncthreads();
    int nl = tid >> 2, q = tid & 3;   // 64 nodes x 4 float4 quads (D=16)
    int n = b * BN + nl;
    if (n >= N) return;
    u64 vis = V[n];
    int c4 = __popcll(NF[nl] & ~vis);
    u64 c = CNT[n];
    int nv = *nvalid;
    float inv = 1.0f / (float)(nv > 0 ? nv : 1);
    float cd[MAXD + 1];
    int total = c4;
#pragma unroll
    for (int d = 0; d < 4; ++d) {
        int x = (int)((c >> (8 * d)) & 0xffull);
        total += x;
        cd[d] = (float)x;
    }
    cd[4] = (float)c4;
    cd[5] = (float)(nv - total);  // depth-5 + unreached

    const float4* e4 = (const float4*)embed;  // [6][4] float4 rows
    float4 acc = {0.f, 0.f, 0.f, 0.f};
#pragma unroll
    for (int d = 0; d <= MAXD; ++d) {
        float4 e = e4[d * 4 + q];
        acc.x += cd[d] * e.x; acc.y += cd[d] * e.y;
        acc.z += cd[d] * e.z; acc.w += cd[d] * e.w;
    }
    acc.x *= inv; acc.y *= inv; acc.z *= inv; acc.w *= inv;
    ((float4*)(out + (size_t)n * 16))[q] = acc;
}

extern "C" void kernel_launch(void* const* d_in, const int* in_sizes, int n_in,
                              void* d_out, int out_size, void* d_ws, size_t ws_size,
                              hipStream_t stream) {
    const int*   h      = (const int*)d_in[0];
    const int*   t      = (const int*)d_in[1];
    const int*   anchor = (const int*)d_in[2];
    const float* embed  = (const float*)d_in[4];
    float*       out    = (float*)d_out;

    int E = in_sizes[0];
    int A = in_sizes[2];               // 32 anchor triples -> 64 sources
    int D = in_sizes[4] / (MAXD + 1);  // 16
    int N = out_size / D;              // 50000
    int NB = (N + BN - 1) >> BSH;      // 782 buckets
    int CE = (E + NW - 1) / NW;        // 1563 edges per chunk
    int CAPC = 2 * CE;                 // 3126 records per chunk (exact)
    (void)D;

    u64* NFg = (u64*)d_ws;
    u64* V   = NFg + N;
    u64* CNT = V + N;
    u64* F2  = CNT + N;
    u64* F3  = F2 + N;
    u32* srcPack   = (u32*)(F3 + N);
    int* nvalid    = (int*)(srcPack + 64);
    u32* bucketCnt = (u32*)(nvalid + 1);
    u32* recs      = bucketCnt + NB;
    u16* segtab    = (u16*)(recs + (size_t)NW * CAPC);
    u32* recs2     = (u32*)(segtab + (size_t)NW * (NB + 1));

    // Only NFg needs zeroing.
    hipMemsetAsync(NFg, 0, (size_t)N * 8, stream);

    size_t shmem = (size_t)(NBMAX + NB + 256 + CAPC) * sizeof(u32);
    chunk_sort<<<NW, NTH, shmem, stream>>>(h, t, E, CE, CAPC, NB, recs, segtab,
                                           anchor, A, NFg, srcPack, nvalid);

    level12_merge<<<NB, NTH, 0, stream>>>(recs, segtab, CAPC, NB, srcPack, NFg,
                                          F2, V, CNT, recs2, bucketCnt, N);
    level3<<<NB, NTH, 0, stream>>>(recs2, bucketCnt, F2, F3, V, CNT, N);
    level4_fin<<<NB, NTH, 0, stream>>>(recs2, bucketCnt, F3, V, CNT,
                                       nvalid, embed, out, N);
}

// Round 10
// 137.989 us; speedup vs baseline: 1.2106x; 1.0061x over previous
//
#include <hip/hip_runtime.h>
#include <hip/hip_bf16.h>

typedef unsigned long long u64;
typedef unsigned int u32;
typedef unsigned short u16;

#define MAXD 5
#define BSH  6
#define BN   64        // nodes per bucket
#define NW   512       // edge chunks (= chunk_sort blocks)
#define NTH  256
#define CAPG 2816      // bucket-major record capacity (mean 2046, +17 sigma)
#define HEMPTY 0xFFFFFFFFu

// ---------------------------------------------------------------------------
// R9 structure (atomic-free chunk sort -> merge-once -> contiguous levels)
// at 138.8us. R10: kill the serialization inside the two big kernels:
//  - chunk_sort: edges staged in LDS (one global pass), 1024-entry scan
//    20 barriers -> 2 (4 entries/thread + wave shfl-scan + cross-wave offs)
//  - level12_merge: 512-seg scan same treatment; per-record 9-step LDS
//    binsearch -> per-thread contiguous j-range with a moving segment
//    pointer (one binsearch/thread), staged into LDS buf; gather + recs2
//    writeout then run stride-NTH (coalesced, 4-wide MLP).
//
// ws: NFg[N] V[N] CNT[N] F2[N] F3[N] (u64) | srcPack[64] nvalid bucketCnt[NB]
//     (u32) | recs[NW*CAPC] (u32) | segtab[NW*(NB+1)] (u16) | recs2[NB*CAPG]
// ---------------------------------------------------------------------------

__global__ __launch_bounds__(NTH) void chunk_sort(
    const int* __restrict__ h, const int* __restrict__ t, int E, int CE, int CAPC,
    int NB, u32* __restrict__ recs, u16* __restrict__ segtab,
    const int* __restrict__ anchor, int A,
    u64* __restrict__ NFg, u32* __restrict__ srcPack, int* __restrict__ nvalid) {
    extern __shared__ u64 dyn[];
    u64* edl   = dyn;                        // [CE] packed (h<<32|t)
    u32* buf   = (u32*)(edl + CE);           // [CAPC] sorted records
    u32* offs  = buf + CAPC;                 // [NB] exclusive offsets
    u32* cur   = offs + NB;                  // [NB] hist -> cursor
    u32* hsKey = cur + NB;                   // [128]
    u32* hsBit = hsKey + 128;                // [128]
    u32* waveSum = hsBit + 128;              // [4]
    int tid = threadIdx.x, c = blockIdx.x;
    int lane = tid & 63, w = tid >> 6;
    int lo = c * CE, hi = min(E, lo + CE);
    int ne = hi - lo;
    int nrec = 2 * ne;

    // stage edges + zero hist + init hash
    for (int i = tid; i < ne; i += NTH)
        edl[i] = ((u64)(u32)h[lo + i] << 32) | (u32)t[lo + i];
    for (int i = tid; i < NB; i += NTH) cur[i] = 0u;
    if (tid < 128) hsKey[tid] = HEMPTY;
    __syncthreads();

    if (tid < 64) {  // wave 0: anchor gather + shfl dedup + hash insert
        int K = 2 * A;  // 64
        int a_ = (tid < K) ? anchor[(tid < A) ? tid : (tid - A)] : 0;
        int my = (tid < K) ? ((tid < A) ? h[a_] : t[a_]) : -1;
        bool uniq = (tid < K);
        for (int j = 0; j < 64; ++j) {
            int o = __shfl(my, j, 64);
            if (j < tid && o == my) uniq = false;
        }
        u64 mask = __ballot(uniq);
        if (c == 0 && tid == 0) *nvalid = (int)__popcll(mask);
        if (uniq) {
            u32 slot = ((u32)my * 2654435761u) >> 25;
            while (atomicCAS(&hsKey[slot], HEMPTY, (u32)my) != HEMPTY)
                slot = (slot + 1) & 127u;
            hsBit[slot] = (u32)tid;
        }
        if (c == 0)
            srcPack[tid] = uniq ? (((u32)my << BSH) | (u32)tid) : HEMPTY;
    }

    // hist from LDS edges (all waves; wave0 joins after hash build)
    for (int i = tid; i < ne; i += NTH) {
        u64 e = edl[i];
        u32 uu = (u32)(e >> 32), vv = (u32)e;
        atomicAdd(&cur[vv >> BSH], 1u);
        atomicAdd(&cur[uu >> BSH], 1u);
    }
    __syncthreads();

    // hierarchical exclusive scan: 4 contiguous entries/thread, 2 barriers
    {
        u32 i0 = (u32)tid * 4;
        u32 aa[4];
#pragma unroll
        for (int k = 0; k < 4; ++k) {
            u32 i = i0 + k;
            aa[k] = (i < (u32)NB) ? cur[i] : 0u;
        }
        u32 sum = aa[0] + aa[1] + aa[2] + aa[3];
        u32 p = sum;
#pragma unroll
        for (int d = 1; d < 64; d <<= 1) {
            u32 x = (u32)__shfl_up((int)p, d, 64);
            if (lane >= d) p += x;
        }
        u32 excl = p - sum;
        if (lane == 63) waveSum[w] = p;
        __syncthreads();
        u32 woff = 0;
        for (int k = 0; k < w; ++k) woff += waveSum[k];
        u32 o0 = woff + excl;
        u32 o1 = o0 + aa[0], o2 = o1 + aa[1], o3 = o2 + aa[2];
        u32 oo[4] = {o0, o1, o2, o3};
#pragma unroll
        for (int k = 0; k < 4; ++k) {
            u32 i = i0 + k;
            if (i < (u32)NB) {
                offs[i] = oo[k];
                segtab[c * (NB + 1) + i] = (u16)oo[k];
                cur[i] = 0u;   // reset as cursor
            }
        }
        if (tid == 0) segtab[c * (NB + 1) + NB] = (u16)nrec;
    }
    __syncthreads();

    auto srcMask = [&](u32 src) -> u64 {
        u32 slot = (src * 2654435761u) >> 25;
        while (true) {
            u32 k = hsKey[slot];
            if (k == src) return 1ull << hsBit[slot];
            if (k == HEMPTY) return 0ull;
            slot = (slot + 1) & 127u;
        }
    };

    // place records + depth-1 NFg push (from LDS edges)
    for (int i = tid; i < ne; i += NTH) {
        u64 e = edl[i];
        u32 uu = (u32)(e >> 32), vv = (u32)e;
        u32 b1 = vv >> BSH;
        buf[offs[b1] + atomicAdd(&cur[b1], 1u)] = (uu << BSH) | (vv & (BN - 1));
        u32 b2 = uu >> BSH;
        buf[offs[b2] + atomicAdd(&cur[b2], 1u)] = (vv << BSH) | (uu & (BN - 1));
        if (uu != vv) {   // self-loop guard keeps NFg == depth-1 newly exactly
            u64 m1 = srcMask(uu);
            if (m1) atomicOr(&NFg[vv], m1);
            u64 m2 = srcMask(vv);
            if (m2) atomicOr(&NFg[uu], m2);
        }
    }
    __syncthreads();
    for (int i = tid; i < nrec; i += NTH) recs[c * CAPC + i] = buf[i];
}

// Depth 1+2 fused + chunk-major -> bucket-major merge (LDS-staged).
__global__ __launch_bounds__(NTH) void level12_merge(
    const u32* __restrict__ recs, const u16* __restrict__ segtab, int CAPC, int NB,
    const u32* __restrict__ srcPack, const u64* __restrict__ NFg,
    u64* __restrict__ F2, u64* __restrict__ V, u64* __restrict__ CNT,
    u32* __restrict__ recs2, u32* __restrict__ bucketCnt, int N) {
    __shared__ u32 s0a[NW];       // segment start within chunk
    __shared__ u32 loff[NW + 1];  // flat exclusive offsets
    __shared__ u32 waveSum[4];
    __shared__ u32 buf[CAPG];     // merged bucket records
    __shared__ u64 NF[BN];
    __shared__ u32 srcL[64];
    int b = blockIdx.x, tid = threadIdx.x;
    int lane = tid & 63, w = tid >> 6;
    if (tid < BN) NF[tid] = 0ull;
    if (tid < 64) srcL[tid] = srcPack[tid];

    // thread owns chunks 2*tid, 2*tid+1 (contiguous for the scan)
    u32 c0 = 2 * tid, c1 = 2 * tid + 1;
    u32 a0 = segtab[c0 * (NB + 1) + b], e0 = segtab[c0 * (NB + 1) + b + 1];
    u32 a1 = segtab[c1 * (NB + 1) + b], e1 = segtab[c1 * (NB + 1) + b + 1];
    s0a[c0] = a0;
    s0a[c1] = a1;
    u32 l0 = e0 - a0, l1 = e1 - a1;
    u32 sum = l0 + l1;
    u32 p = sum;
#pragma unroll
    for (int d = 1; d < 64; d <<= 1) {
        u32 x = (u32)__shfl_up((int)p, d, 64);
        if (lane >= d) p += x;
    }
    u32 excl = p - sum;
    if (lane == 63) waveSum[w] = p;
    __syncthreads();
    u32 woff = 0;
    for (int k = 0; k < w; ++k) woff += waveSum[k];
    u32 base = woff + excl;
    loff[c0] = base;
    loff[c1] = base + l0;
    if (tid == NTH - 1) loff[NW] = base + l0 + l1;
    __syncthreads();

    u32 T = min(loff[NW], (u32)CAPG);

    // per-thread contiguous range; one binsearch, then moving pointer
    u32 per = (T + NTH - 1) / NTH;
    u32 j0 = min((u32)tid * per, T), j1 = min(j0 + per, T);
    if (j0 < j1) {
        int c = 0;
#pragma unroll
        for (int step = 256; step >= 1; step >>= 1)
            if (c + step <= NW - 1 && loff[c + step] <= j0) c += step;
        for (u32 j = j0; j < j1; ++j) {
            while (loff[c + 1] <= j) ++c;
            buf[j] = recs[(u32)c * CAPC + s0a[c] + (j - loff[c])];
        }
    }
    __syncthreads();

    // gather depth-2 from LDS records + coalesced bucket-major writeout
    u32 o0 = (u32)b * CAPG;
    u32 r = tid;
    for (; r + 3u * NTH < T; r += 4u * NTH) {
        u32 r0 = buf[r],           r1 = buf[r + NTH];
        u32 r2 = buf[r + 2 * NTH], r3 = buf[r + 3 * NTH];
        recs2[o0 + r] = r0;
        recs2[o0 + r + NTH] = r1;
        recs2[o0 + r + 2 * NTH] = r2;
        recs2[o0 + r + 3 * NTH] = r3;
        u64 f0 = NFg[r0 >> BSH], f1 = NFg[r1 >> BSH];
        u64 f2 = NFg[r2 >> BSH], f3 = NFg[r3 >> BSH];
        if (f0) atomicOr(&NF[r0 & (BN - 1)], f0);
        if (f1) atomicOr(&NF[r1 & (BN - 1)], f1);
        if (f2) atomicOr(&NF[r2 & (BN - 1)], f2);
        if (f3) atomicOr(&NF[r3 & (BN - 1)], f3);
    }
    for (; r < T; r += NTH) {
        u32 r0 = buf[r];
        recs2[o0 + r] = r0;
        u64 f0 = NFg[r0 >> BSH];
        if (f0) atomicOr(&NF[r0 & (BN - 1)], f0);
    }
    __syncthreads();
    if (tid == 0) bucketCnt[b] = T;
    if (tid < BN) {
        int n = b * BN + tid;
        if (n < N) {
            u64 srcbit = 0ull;
            for (int k = 0; k < 64; ++k) {
                u32 pk = srcL[k];
                if (pk != HEMPTY && (int)(pk >> BSH) == n)
                    srcbit |= 1ull << (pk & (BN - 1));
            }
            u64 nf1 = NFg[n];
            u64 v1 = srcbit | nf1;
            u64 newly2 = NF[tid] & ~v1;
            V[n] = v1 | newly2;
            F2[n] = newly2;
            CNT[n] = (srcbit ? 1ull : 0ull)
                   | ((u64)__popcll(nf1) << 8)
                   | ((u64)__popcll(newly2) << 16);
        }
    }
}

// Depth 3: contiguous bucket-major gather, 4-wide unrolled.
__global__ __launch_bounds__(NTH) void level3(
    const u32* __restrict__ recs2, const u32* __restrict__ bucketCnt,
    const u64* __restrict__ Fin, u64* __restrict__ Fout,
    u64* __restrict__ V, u64* __restrict__ CNT, int N) {
    __shared__ u64 NF[BN];
    int b = blockIdx.x, tid = threadIdx.x;
    u32 o0 = (u32)b * CAPG;
    u32 cnt = bucketCnt[b];
    if (tid < BN) NF[tid] = 0ull;
    __syncthreads();
    u32 r = tid;
    for (; r + 3u * NTH < cnt; r += 4u * NTH) {
        u32 c0 = recs2[o0 + r],           c1 = recs2[o0 + r + NTH];
        u32 c2 = recs2[o0 + r + 2 * NTH], c3 = recs2[o0 + r + 3 * NTH];
        u64 f0 = Fin[c0 >> BSH], f1 = Fin[c1 >> BSH];
        u64 f2 = Fin[c2 >> BSH], f3 = Fin[c3 >> BSH];
        if (f0) atomicOr(&NF[c0 & (BN - 1)], f0);
        if (f1) atomicOr(&NF[c1 & (BN - 1)], f1);
        if (f2) atomicOr(&NF[c2 & (BN - 1)], f2);
        if (f3) atomicOr(&NF[c3 & (BN - 1)], f3);
    }
    for (; r < cnt; r += NTH) {
        u32 c0 = recs2[o0 + r];
        u64 f0 = Fin[c0 >> BSH];
        if (f0) atomicOr(&NF[c0 & (BN - 1)], f0);
    }
    __syncthreads();
    if (tid < BN) {
        int n = b * BN + tid;
        if (n < N) {
            u64 vis = V[n];
            u64 newly = NF[tid] & ~vis;
            Fout[n] = newly;
            if (newly) {
                V[n] = vis | newly;
                CNT[n] += (u64)__popcll(newly) << 24;
            }
        }
    }
}

// Depth 4 fused with the output matmul (quad lane q writes float4 q, D=16).
__global__ __launch_bounds__(NTH) void level4_fin(
    const u32* __restrict__ recs2, const u32* __restrict__ bucketCnt,
    const u64* __restrict__ Fin, const u64* __restrict__ V,
    const u64* __restrict__ CNT, const int* __restrict__ nvalid,
    const float* __restrict__ embed, float* __restrict__ out, int N) {
    __shared__ u64 NF[BN];
    int b = blockIdx.x, tid = threadIdx.x;
    u32 o0 = (u32)b * CAPG;
    u32 cnt = bucketCnt[b];
    if (tid < BN) NF[tid] = 0ull;
    __syncthreads();
    u32 r = tid;
    for (; r + 3u * NTH < cnt; r += 4u * NTH) {
        u32 c0 = recs2[o0 + r],           c1 = recs2[o0 + r + NTH];
        u32 c2 = recs2[o0 + r + 2 * NTH], c3 = recs2[o0 + r + 3 * NTH];
        u64 f0 = Fin[c0 >> BSH], f1 = Fin[c1 >> BSH];
        u64 f2 = Fin[c2 >> BSH], f3 = Fin[c3 >> BSH];
        if (f0) atomicOr(&NF[c0 & (BN - 1)], f0);
        if (f1) atomicOr(&NF[c1 & (BN - 1)], f1);
        if (f2) atomicOr(&NF[c2 & (BN - 1)], f2);
        if (f3) atomicOr(&NF[c3 & (BN - 1)], f3);
    }
    for (; r < cnt; r += NTH) {
        u32 c0 = recs2[o0 + r];
        u64 f0 = Fin[c0 >> BSH];
        if (f0) atomicOr(&NF[c0 & (BN - 1)], f0);
    }
    __syncthreads();
    int nl = tid >> 2, q = tid & 3;   // 64 nodes x 4 float4 quads (D=16)
    int n = b * BN + nl;
    if (n >= N) return;
    u64 vis = V[n];
    int c4 = __popcll(NF[nl] & ~vis);
    u64 c = CNT[n];
    int nv = *nvalid;
    float inv = 1.0f / (float)(nv > 0 ? nv : 1);
    float cd[MAXD + 1];
    int total = c4;
#pragma unroll
    for (int d = 0; d < 4; ++d) {
        int x = (int)((c >> (8 * d)) & 0xffull);
        total += x;
        cd[d] = (float)x;
    }
    cd[4] = (float)c4;
    cd[5] = (float)(nv - total);  // depth-5 + unreached

    const float4* e4 = (const float4*)embed;  // [6][4] float4 rows
    float4 acc = {0.f, 0.f, 0.f, 0.f};
#pragma unroll
    for (int d = 0; d <= MAXD; ++d) {
        float4 e = e4[d * 4 + q];
        acc.x += cd[d] * e.x; acc.y += cd[d] * e.y;
        acc.z += cd[d] * e.z; acc.w += cd[d] * e.w;
    }
    acc.x *= inv; acc.y *= inv; acc.z *= inv; acc.w *= inv;
    ((float4*)(out + (size_t)n * 16))[q] = acc;
}

extern "C" void kernel_launch(void* const* d_in, const int* in_sizes, int n_in,
                              void* d_out, int out_size, void* d_ws, size_t ws_size,
                              hipStream_t stream) {
    const int*   h      = (const int*)d_in[0];
    const int*   t      = (const int*)d_in[1];
    const int*   anchor = (const int*)d_in[2];
    const float* embed  = (const float*)d_in[4];
    float*       out    = (float*)d_out;

    int E = in_sizes[0];
    int A = in_sizes[2];               // 32 anchor triples -> 64 sources
    int D = in_sizes[4] / (MAXD + 1);  // 16
    int N = out_size / D;              // 50000
    int NB = (N + BN - 1) >> BSH;      // 782 buckets
    int CE = (E + NW - 1) / NW;        // 1563 edges per chunk
    int CAPC = 2 * CE;                 // 3126 records per chunk (exact)
    (void)D;

    u64* NFg = (u64*)d_ws;
    u64* V   = NFg + N;
    u64* CNT = V + N;
    u64* F2  = CNT + N;
    u64* F3  = F2 + N;
    u32* srcPack   = (u32*)(F3 + N);
    int* nvalid    = (int*)(srcPack + 64);
    u32* bucketCnt = (u32*)(nvalid + 1);
    u32* recs      = bucketCnt + NB;
    u16* segtab    = (u16*)(recs + (size_t)NW * CAPC);
    u32* recs2     = (u32*)(segtab + (size_t)NW * (NB + 1));

    // Only NFg needs zeroing.
    hipMemsetAsync(NFg, 0, (size_t)N * 8, stream);

    size_t shmem = (size_t)CE * 8
                 + (size_t)(CAPC + NB + NB + 128 + 128 + 4) * sizeof(u32);
    chunk_sort<<<NW, NTH, shmem, stream>>>(h, t, E, CE, CAPC, NB, recs, segtab,
                                           anchor, A, NFg, srcPack, nvalid);

    level12_merge<<<NB, NTH, 0, stream>>>(recs, segtab, CAPC, NB, srcPack, NFg,
                                          F2, V, CNT, recs2, bucketCnt, N);
    level3<<<NB, NTH, 0, stream>>>(recs2, bucketCnt, F2, F3, V, CNT, N);
    level4_fin<<<NB, NTH, 0, stream>>>(recs2, bucketCnt, F3, V, CNT,
                                       nvalid, embed, out, N);
}

// Round 11
// 135.048 us; speedup vs baseline: 1.2369x; 1.0218x over previous
//
#include <hip/hip_runtime.h>
#include <hip/hip_bf16.h>

typedef unsigned long long u64;
typedef unsigned int u32;
typedef unsigned short u16;

#define MAXD 5
#define BSH  6
#define BN   64        // nodes per bucket
#define NW   1024      // edge chunks (= chunk_sort blocks)
#define NTH  256
#define CAPG 2816      // bucket-major record capacity (mean 2046, +17 sigma)
#define HEMPTY 0xFFFFFFFFu

// ---------------------------------------------------------------------------
// R10 lesson: scan/binsearch serialization wasn't the cost (+0.8us). R11
// probes occupancy: NW 512->1024 halves per-block LDS on the two heavy
// kernels (chunk_sort drops the LDS edge staging entirely -> 13.2KB,
// 4 blocks/CU = 16 waves/CU; level12_merge scans 1024 segments 4/thread).
// Edges are read twice from global (coalesced, ~+1us) instead of staged.
//
// ws: NFg[N] V[N] CNT[N] F2[N] F3[N] (u64) | srcPack[64] nvalid bucketCnt[NB]
//     (u32) | recs[NW*CAPC] (u32) | segtab[NW*(NB+1)] (u16) | recs2[NB*CAPG]
// ---------------------------------------------------------------------------

__global__ __launch_bounds__(NTH) void chunk_sort(
    const int* __restrict__ h, const int* __restrict__ t, int E, int CE, int CAPC,
    int NB, u32* __restrict__ recs, u16* __restrict__ segtab,
    const int* __restrict__ anchor, int A,
    u64* __restrict__ NFg, u32* __restrict__ srcPack, int* __restrict__ nvalid) {
    extern __shared__ u32 sh[];
    u32* buf   = sh;                         // [CAPC] sorted records
    u32* offs  = buf + CAPC;                 // [NB] exclusive offsets
    u32* cur   = offs + NB;                  // [NB] hist -> cursor
    u32* hsKey = cur + NB;                   // [128]
    u32* hsBit = hsKey + 128;                // [128]
    u32* waveSum = hsBit + 128;              // [4]
    int tid = threadIdx.x, c = blockIdx.x;
    int lane = tid & 63, w = tid >> 6;
    int lo = c * CE, hi = min(E, lo + CE);
    int ne = hi - lo;
    int nrec = 2 * ne;

    for (int i = tid; i < NB; i += NTH) cur[i] = 0u;
    if (tid < 128) hsKey[tid] = HEMPTY;
    __syncthreads();

    if (tid < 64) {  // wave 0: anchor gather + shfl dedup + hash insert
        int K = 2 * A;  // 64
        int a_ = (tid < K) ? anchor[(tid < A) ? tid : (tid - A)] : 0;
        int my = (tid < K) ? ((tid < A) ? h[a_] : t[a_]) : -1;
        bool uniq = (tid < K);
        for (int j = 0; j < 64; ++j) {
            int o = __shfl(my, j, 64);
            if (j < tid && o == my) uniq = false;
        }
        u64 mask = __ballot(uniq);
        if (c == 0 && tid == 0) *nvalid = (int)__popcll(mask);
        if (uniq) {
            u32 slot = ((u32)my * 2654435761u) >> 25;
            while (atomicCAS(&hsKey[slot], HEMPTY, (u32)my) != HEMPTY)
                slot = (slot + 1) & 127u;
            hsBit[slot] = (u32)tid;
        }
        if (c == 0)
            srcPack[tid] = uniq ? (((u32)my << BSH) | (u32)tid) : HEMPTY;
    }

    // pass 1: hist (coalesced global edge reads)
    for (int i = tid; i < ne; i += NTH) {
        u32 uu = (u32)h[lo + i], vv = (u32)t[lo + i];
        atomicAdd(&cur[vv >> BSH], 1u);
        atomicAdd(&cur[uu >> BSH], 1u);
    }
    __syncthreads();

    // hierarchical exclusive scan: 4 contiguous entries/thread, 2 barriers
    {
        u32 i0 = (u32)tid * 4;
        u32 aa[4];
#pragma unroll
        for (int k = 0; k < 4; ++k) {
            u32 i = i0 + k;
            aa[k] = (i < (u32)NB) ? cur[i] : 0u;
        }
        u32 sum = aa[0] + aa[1] + aa[2] + aa[3];
        u32 p = sum;
#pragma unroll
        for (int d = 1; d < 64; d <<= 1) {
            u32 x = (u32)__shfl_up((int)p, d, 64);
            if (lane >= d) p += x;
        }
        u32 excl = p - sum;
        if (lane == 63) waveSum[w] = p;
        __syncthreads();
        u32 woff = 0;
        for (int k = 0; k < w; ++k) woff += waveSum[k];
        u32 o0 = woff + excl;
        u32 oo[4] = {o0, o0 + aa[0], o0 + aa[0] + aa[1],
                     o0 + aa[0] + aa[1] + aa[2]};
#pragma unroll
        for (int k = 0; k < 4; ++k) {
            u32 i = i0 + k;
            if (i < (u32)NB) {
                offs[i] = oo[k];
                segtab[c * (NB + 1) + i] = (u16)oo[k];
                cur[i] = 0u;   // reset as cursor
            }
        }
        if (tid == 0) segtab[c * (NB + 1) + NB] = (u16)nrec;
    }
    __syncthreads();

    auto srcMask = [&](u32 src) -> u64 {
        u32 slot = (src * 2654435761u) >> 25;
        while (true) {
            u32 k = hsKey[slot];
            if (k == src) return 1ull << hsBit[slot];
            if (k == HEMPTY) return 0ull;
            slot = (slot + 1) & 127u;
        }
    };

    // pass 2: place records + depth-1 NFg push (edges L2-hot from pass 1)
    for (int i = tid; i < ne; i += NTH) {
        u32 uu = (u32)h[lo + i], vv = (u32)t[lo + i];
        u32 b1 = vv >> BSH;
        buf[offs[b1] + atomicAdd(&cur[b1], 1u)] = (uu << BSH) | (vv & (BN - 1));
        u32 b2 = uu >> BSH;
        buf[offs[b2] + atomicAdd(&cur[b2], 1u)] = (vv << BSH) | (uu & (BN - 1));
        if (uu != vv) {   // self-loop guard keeps NFg == depth-1 newly exactly
            u64 m1 = srcMask(uu);
            if (m1) atomicOr(&NFg[vv], m1);
            u64 m2 = srcMask(vv);
            if (m2) atomicOr(&NFg[uu], m2);
        }
    }
    __syncthreads();
    for (int i = tid; i < nrec; i += NTH) recs[c * CAPC + i] = buf[i];
}

// Depth 1+2 fused + chunk-major -> bucket-major merge (LDS-staged).
__global__ __launch_bounds__(NTH) void level12_merge(
    const u32* __restrict__ recs, const u16* __restrict__ segtab, int CAPC, int NB,
    const u32* __restrict__ srcPack, const u64* __restrict__ NFg,
    u64* __restrict__ F2, u64* __restrict__ V, u64* __restrict__ CNT,
    u32* __restrict__ recs2, u32* __restrict__ bucketCnt, int N) {
    __shared__ u16 s0a[NW];       // segment start within chunk (fits u16)
    __shared__ u32 loff[NW + 1];  // flat exclusive offsets
    __shared__ u32 waveSum[4];
    __shared__ u32 buf[CAPG];     // merged bucket records
    __shared__ u64 NF[BN];
    __shared__ u32 srcL[64];
    int b = blockIdx.x, tid = threadIdx.x;
    int lane = tid & 63, w = tid >> 6;
    if (tid < BN) NF[tid] = 0ull;
    if (tid < 64) srcL[tid] = srcPack[tid];

    // thread owns 4 contiguous chunks for the scan
    u32 c0 = (u32)tid * 4;
    u32 aa[4], ll[4];
#pragma unroll
    for (int k = 0; k < 4; ++k) {
        u32 c = c0 + k;
        u32 a = segtab[c * (NB + 1) + b];
        u32 e = segtab[c * (NB + 1) + b + 1];
        s0a[c] = (u16)a;
        aa[k] = a;
        ll[k] = e - a;
    }
    u32 sum = ll[0] + ll[1] + ll[2] + ll[3];
    u32 p = sum;
#pragma unroll
    for (int d = 1; d < 64; d <<= 1) {
        u32 x = (u32)__shfl_up((int)p, d, 64);
        if (lane >= d) p += x;
    }
    u32 excl = p - sum;
    if (lane == 63) waveSum[w] = p;
    __syncthreads();
    u32 woff = 0;
    for (int k = 0; k < w; ++k) woff += waveSum[k];
    u32 base = woff + excl;
    loff[c0]     = base;
    loff[c0 + 1] = base + ll[0];
    loff[c0 + 2] = base + ll[0] + ll[1];
    loff[c0 + 3] = base + ll[0] + ll[1] + ll[2];
    if (tid == NTH - 1) loff[NW] = base + sum;
    (void)aa;
    __syncthreads();

    u32 T = min(loff[NW], (u32)CAPG);

    // per-thread contiguous range; one binsearch, then moving pointer
    u32 per = (T + NTH - 1) / NTH;
    u32 j0 = min((u32)tid * per, T), j1 = min(j0 + per, T);
    if (j0 < j1) {
        int c = 0;
#pragma unroll
        for (int step = 512; step >= 1; step >>= 1)
            if (c + step <= NW - 1 && loff[c + step] <= j0) c += step;
        for (u32 j = j0; j < j1; ++j) {
            while (loff[c + 1] <= j) ++c;
            buf[j] = recs[(u32)c * CAPC + (u32)s0a[c] + (j - loff[c])];
        }
    }
    __syncthreads();

    // gather depth-2 from LDS records + coalesced bucket-major writeout
    u32 o0 = (u32)b * CAPG;
    u32 r = tid;
    for (; r + 3u * NTH < T; r += 4u * NTH) {
        u32 r0 = buf[r],           r1 = buf[r + NTH];
        u32 r2 = buf[r + 2 * NTH], r3 = buf[r + 3 * NTH];
        recs2[o0 + r] = r0;
        recs2[o0 + r + NTH] = r1;
        recs2[o0 + r + 2 * NTH] = r2;
        recs2[o0 + r + 3 * NTH] = r3;
        u64 f0 = NFg[r0 >> BSH], f1 = NFg[r1 >> BSH];
        u64 f2 = NFg[r2 >> BSH], f3 = NFg[r3 >> BSH];
        if (f0) atomicOr(&NF[r0 & (BN - 1)], f0);
        if (f1) atomicOr(&NF[r1 & (BN - 1)], f1);
        if (f2) atomicOr(&NF[r2 & (BN - 1)], f2);
        if (f3) atomicOr(&NF[r3 & (BN - 1)], f3);
    }
    for (; r < T; r += NTH) {
        u32 r0 = buf[r];
        recs2[o0 + r] = r0;
        u64 f0 = NFg[r0 >> BSH];
        if (f0) atomicOr(&NF[r0 & (BN - 1)], f0);
    }
    __syncthreads();
    if (tid == 0) bucketCnt[b] = T;
    if (tid < BN) {
        int n = b * BN + tid;
        if (n < N) {
            u64 srcbit = 0ull;
            for (int k = 0; k < 64; ++k) {
                u32 pk = srcL[k];
                if (pk != HEMPTY && (int)(pk >> BSH) == n)
                    srcbit |= 1ull << (pk & (BN - 1));
            }
            u64 nf1 = NFg[n];
            u64 v1 = srcbit | nf1;
            u64 newly2 = NF[tid] & ~v1;
            V[n] = v1 | newly2;
            F2[n] = newly2;
            CNT[n] = (srcbit ? 1ull : 0ull)
                   | ((u64)__popcll(nf1) << 8)
                   | ((u64)__popcll(newly2) << 16);
        }
    }
}

// Depth 3: contiguous bucket-major gather, 4-wide unrolled.
__global__ __launch_bounds__(NTH) void level3(
    const u32* __restrict__ recs2, const u32* __restrict__ bucketCnt,
    const u64* __restrict__ Fin, u64* __restrict__ Fout,
    u64* __restrict__ V, u64* __restrict__ CNT, int N) {
    __shared__ u64 NF[BN];
    int b = blockIdx.x, tid = threadIdx.x;
    u32 o0 = (u32)b * CAPG;
    u32 cnt = bucketCnt[b];
    if (tid < BN) NF[tid] = 0ull;
    __syncthreads();
    u32 r = tid;
    for (; r + 3u * NTH < cnt; r += 4u * NTH) {
        u32 c0 = recs2[o0 + r],           c1 = recs2[o0 + r + NTH];
        u32 c2 = recs2[o0 + r + 2 * NTH], c3 = recs2[o0 + r + 3 * NTH];
        u64 f0 = Fin[c0 >> BSH], f1 = Fin[c1 >> BSH];
        u64 f2 = Fin[c2 >> BSH], f3 = Fin[c3 >> BSH];
        if (f0) atomicOr(&NF[c0 & (BN - 1)], f0);
        if (f1) atomicOr(&NF[c1 & (BN - 1)], f1);
        if (f2) atomicOr(&NF[c2 & (BN - 1)], f2);
        if (f3) atomicOr(&NF[c3 & (BN - 1)], f3);
    }
    for (; r < cnt; r += NTH) {
        u32 c0 = recs2[o0 + r];
        u64 f0 = Fin[c0 >> BSH];
        if (f0) atomicOr(&NF[c0 & (BN - 1)], f0);
    }
    __syncthreads();
    if (tid < BN) {
        int n = b * BN + tid;
        if (n < N) {
            u64 vis = V[n];
            u64 newly = NF[tid] & ~vis;
            Fout[n] = newly;
            if (newly) {
                V[n] = vis | newly;
                CNT[n] += (u64)__popcll(newly) << 24;
            }
        }
    }
}

// Depth 4 fused with the output matmul (quad lane q writes float4 q, D=16).
__global__ __launch_bounds__(NTH) void level4_fin(
    const u32* __restrict__ recs2, const u32* __restrict__ bucketCnt,
    const u64* __restrict__ Fin, const u64* __restrict__ V,
    const u64* __restrict__ CNT, const int* __restrict__ nvalid,
    const float* __restrict__ embed, float* __restrict__ out, int N) {
    __shared__ u64 NF[BN];
    int b = blockIdx.x, tid = threadIdx.x;
    u32 o0 = (u32)b * CAPG;
    u32 cnt = bucketCnt[b];
    if (tid < BN) NF[tid] = 0ull;
    __syncthreads();
    u32 r = tid;
    for (; r + 3u * NTH < cnt; r += 4u * NTH) {
        u32 c0 = recs2[o0 + r],           c1 = recs2[o0 + r + NTH];
        u32 c2 = recs2[o0 + r + 2 * NTH], c3 = recs2[o0 + r + 3 * NTH];
        u64 f0 = Fin[c0 >> BSH], f1 = Fin[c1 >> BSH];
        u64 f2 = Fin[c2 >> BSH], f3 = Fin[c3 >> BSH];
        if (f0) atomicOr(&NF[c0 & (BN - 1)], f0);
        if (f1) atomicOr(&NF[c1 & (BN - 1)], f1);
        if (f2) atomicOr(&NF[c2 & (BN - 1)], f2);
        if (f3) atomicOr(&NF[c3 & (BN - 1)], f3);
    }
    for (; r < cnt; r += NTH) {
        u32 c0 = recs2[o0 + r];
        u64 f0 = Fin[c0 >> BSH];
        if (f0) atomicOr(&NF[c0 & (BN - 1)], f0);
    }
    __syncthreads();
    int nl = tid >> 2, q = tid & 3;   // 64 nodes x 4 float4 quads (D=16)
    int n = b * BN + nl;
    if (n >= N) return;
    u64 vis = V[n];
    int c4 = __popcll(NF[nl] & ~vis);
    u64 c = CNT[n];
    int nv = *nvalid;
    float inv = 1.0f / (float)(nv > 0 ? nv : 1);
    float cd[MAXD + 1];
    int total = c4;
#pragma unroll
    for (int d = 0; d < 4; ++d) {
        int x = (int)((c >> (8 * d)) & 0xffull);
        total += x;
        cd[d] = (float)x;
    }
    cd[4] = (float)c4;
    cd[5] = (float)(nv - total);  // depth-5 + unreached

    const float4* e4 = (const float4*)embed;  // [6][4] float4 rows
    float4 acc = {0.f, 0.f, 0.f, 0.f};
#pragma unroll
    for (int d = 0; d <= MAXD; ++d) {
        float4 e = e4[d * 4 + q];
        acc.x += cd[d] * e.x; acc.y += cd[d] * e.y;
        acc.z += cd[d] * e.z; acc.w += cd[d] * e.w;
    }
    acc.x *= inv; acc.y *= inv; acc.z *= inv; acc.w *= inv;
    ((float4*)(out + (size_t)n * 16))[q] = acc;
}

extern "C" void kernel_launch(void* const* d_in, const int* in_sizes, int n_in,
                              void* d_out, int out_size, void* d_ws, size_t ws_size,
                              hipStream_t stream) {
    const int*   h      = (const int*)d_in[0];
    const int*   t      = (const int*)d_in[1];
    const int*   anchor = (const int*)d_in[2];
    const float* embed  = (const float*)d_in[4];
    float*       out    = (float*)d_out;

    int E = in_sizes[0];
    int A = in_sizes[2];               // 32 anchor triples -> 64 sources
    int D = in_sizes[4] / (MAXD + 1);  // 16
    int N = out_size / D;              // 50000
    int NB = (N + BN - 1) >> BSH;      // 782 buckets
    int CE = (E + NW - 1) / NW;        // 782 edges per chunk
    int CAPC = 2 * CE;                 // 1564 records per chunk (exact)
    (void)D;

    u64* NFg = (u64*)d_ws;
    u64* V   = NFg + N;
    u64* CNT = V + N;
    u64* F2  = CNT + N;
    u64* F3  = F2 + N;
    u32* srcPack   = (u32*)(F3 + N);
    int* nvalid    = (int*)(srcPack + 64);
    u32* bucketCnt = (u32*)(nvalid + 1);
    u32* recs      = bucketCnt + NB;
    u16* segtab    = (u16*)(recs + (size_t)NW * CAPC);
    u32* recs2     = (u32*)(segtab + (size_t)NW * (NB + 1));

    // Only NFg needs zeroing.
    hipMemsetAsync(NFg, 0, (size_t)N * 8, stream);

    size_t shmem = (size_t)(CAPC + 2 * NB + 260) * sizeof(u32);
    chunk_sort<<<NW, NTH, shmem, stream>>>(h, t, E, CE, CAPC, NB, recs, segtab,
                                           anchor, A, NFg, srcPack, nvalid);

    level12_merge<<<NB, NTH, 0, stream>>>(recs, segtab, CAPC, NB, srcPack, NFg,
                                          F2, V, CNT, recs2, bucketCnt, N);
    level3<<<NB, NTH, 0, stream>>>(recs2, bucketCnt, F2, F3, V, CNT, N);
    level4_fin<<<NB, NTH, 0, stream>>>(recs2, bucketCnt, F3, V, CNT,
                                       nvalid, embed, out, N);
}